// Round 4
// baseline (754.625 us; speedup 1.0000x reference)
//
#include <hip/hip_runtime.h>

typedef unsigned int uint;
typedef unsigned short ushort_t;
typedef __attribute__((ext_vector_type(8))) short bf16x8_t;   // 8 bf16 (4 VGPRs)
typedef __attribute__((ext_vector_type(4))) float f32x4_t;    // MFMA acc

// Problem constants
constexpr int Bsz = 4096, NX = 64, NU = 16, NXU = 80, HID = 256, Hh = 50;
constexpr long NS = (long)Bsz * Hh * NU;   // noise per-iteration stride: 3,276,800
// Output offsets (floats), concatenated in return order
constexpr int O1 = 65536;                  // x_traj  (B,51,64)
constexpr int O2 = 13434880;               // pred    (B,50,64)
constexpr int O3 = 26542080;               // gx      (B,50,64)
constexpr int O4 = 39649280;               // gu      (B,50,16)
constexpr int XT_PITCH = (Hh + 1) * NX;    // 3264
constexpr int PR_PITCH = Hh * NX;          // 3200
constexpr int U_PITCH = Hh * NU;           // 800

// LDS strides (padded)
constexpr int W1S  = 260;  // fallback: W1L row stride (floats)
constexpr int W1TS = 84;   // ker_roll: W1T [c][kk] stride (floats); 336 B = 21*16
constexpr int HS   = 264;  // fallback hRT stride
constexpr int HSR  = 260;  // ker_roll hRT [r][kk] stride (floats); 1040 B = 65*16
constexpr int ZTS  = 20;   // ker_roll zT [kk][16] stride (floats); 80 B (b128-alignable)
constexpr int TS   = 264;  // tT row stride (shorts)   (fallback kernel only)
constexpr int W2S  = 264;  // W2T row stride (shorts)
constexpr int TLS  = 264;  // K2 LDS row stride (shorts); 264*2=528 B, 16B-aligned

constexpr long T_BYTES = (long)Bsz * Hh * HID * 2;   // 104,857,600 B in d_ws

__device__ __forceinline__ float tanh_fast(float x) {
    float e = __expf(2.0f * x);
    return 1.0f - 2.0f / (e + 1.0f);   // safe at +/-inf
}
__device__ __forceinline__ uint f2bf_u(float x) {
    uint b = __float_as_uint(x);
    return (b + 0x7FFFu + ((b >> 16) & 1u)) >> 16;   // RNE, low 16 bits valid
}
__device__ __forceinline__ float bf2f(ushort_t u) {
    return __uint_as_float(((uint)u) << 16);
}
__device__ __forceinline__ void unpack8(uint4 v, float* f) {
    f[0] = __uint_as_float(v.x << 16); f[1] = __uint_as_float(v.x & 0xFFFF0000u);
    f[2] = __uint_as_float(v.y << 16); f[3] = __uint_as_float(v.y & 0xFFFF0000u);
    f[4] = __uint_as_float(v.z << 16); f[5] = __uint_as_float(v.z & 0xFFFF0000u);
    f[6] = __uint_as_float(v.w << 16); f[7] = __uint_as_float(v.w & 0xFFFF0000u);
}

// =====================================================================
// K1: sequential rollout, 16 batch rows/block, 256 blocks, 512 threads.
// LDS-BW-minimizing column decomposition:
//   P1: thread (half=tid>>8, c=tid&255) owns a[8 rows][col c].
//       W1 transposed in LDS ([c][kk]) -> per-lane contiguous b128;
//       z read as wave-uniform broadcast b128 (bank-free).
//   P2: thread (rp=tid>>6, d=tid&63) owns x[2 rows][col d].
//       W2 bf16 [d][kk] per-lane uint4; h broadcast b128.
// Per-output kk-order unchanged -> bitwise-identical trajectory.
// LDS traffic/step: ~2.03 MB -> ~0.46 MB.
// =====================================================================
__global__ __launch_bounds__(512, 2) void ker_roll(const float* __restrict__ x0,
                                                   const float* __restrict__ W1,
                                                   const float* __restrict__ b1,
                                                   const float* __restrict__ W2,
                                                   const float* __restrict__ noise,
                                                   const int* __restrict__ nit_p,
                                                   float* __restrict__ out,
                                                   ushort_t* __restrict__ tg) {
    __shared__ __align__(16) float    W1T[HID * W1TS];  // 86,016 B  [c][kk]
    __shared__ __align__(16) ushort_t W2T[NX * W2S];    // 33,792 B  [d][c]
    __shared__ __align__(16) float    hRT[16 * HSR];    // 16,640 B  [r][kk]
    __shared__ __align__(16) float    zT[NXU * ZTS];    //  6,400 B  [kk][16]
    __shared__ float b1L[HID];                          //  1,024 B
    __shared__ float sL[HID];                           //  1,024 B
    // total 144,896 B -> 1 block (8 waves) / CU

    const int tid = threadIdx.x;
    const int b0 = blockIdx.x * 16;
    const int nit = nit_p[0];

    // stage W1 transposed [c][kk]
    for (int i = tid; i < NXU * HID; i += 512) {
        int kk = i >> 8, c = i & 255;
        W1T[c * W1TS + kk] = W1[i];
    }
    for (int i = tid; i < HID * NX; i += 512) {
        int c = i >> 6, d = i & 63;
        W2T[d * W2S + c] = (ushort_t)f2bf_u(W2[i]);
    }
    if (tid < HID) b1L[tid] = b1[tid];
    for (int i = tid; i < 16 * NX; i += 512) {
        int r = i >> 6, d = i & 63;
        float v = x0[(b0 + r) * NX + d];
        zT[d * ZTS + r] = v;
        out[O1 + (b0 + r) * XT_PITCH + d] = v;
    }
    const int r16n = (tid >> 4) & 15, q16n = tid & 15;   // control-tile mapping (tid<256)
    if (tid < 256) {
        long base = (long)(b0 + r16n) * U_PITCH + q16n;
        float s = 0.f;
        for (int it = 0; it < nit - 1; ++it) s += noise[(long)it * NS + base];
        zT[(NX + q16n) * ZTS + r16n] = 0.001f * s;
        out[(b0 + r16n) * NU + q16n] = 0.001f * (s + noise[(long)(nit - 1) * NS + base]);
    }
    __syncthreads();
    if (tid < HID) {
        float s = 0.f;
        for (int d = 0; d < NX; ++d) s += bf2f(W2T[d * W2S + tid]);
        sL[tid] = 0.1f * s;   // consumed after next barrier (loop-top)
    }

    const int cP1 = tid & 255, half = tid >> 8;   // P1: rows 8*half..+7, col cP1
    const int dP2 = tid & 63,  rp = tid >> 6;     // P2: rows {2rp,2rp+1}, col dP2
    const uint* W2Tu = (const uint*)W2T;

    for (int k = 0; k < Hh; ++k) {
        __syncthreads();

        // prefetch next-step controls (tid<256 handles the 16x16 control tile)
        float v9[9];
        const bool fast = (k < Hh - 1) && (nit == 10);
        long nbase = (long)(b0 + r16n) * U_PITCH + (k + 1) * NU + q16n;
        if (fast && tid < 256) {
            #pragma unroll
            for (int it = 0; it < 9; ++it) v9[it] = noise[(long)it * NS + nbase];
        }

        // ---- P1: a[r][c] = b1[c] + sum_kk z[r][kk]*W1[kk][c] ----
        float a_[8];
        {
            float bj = b1L[cP1];
            #pragma unroll
            for (int i = 0; i < 8; ++i) a_[i] = bj;
        }
        const float* w1c = &W1T[cP1 * W1TS];
        #pragma unroll 4
        for (int kc = 0; kc < 20; ++kc) {
            float4 wv = *(const float4*)&w1c[4 * kc];       // per-lane, contiguous
            float ww[4] = {wv.x, wv.y, wv.z, wv.w};
            #pragma unroll
            for (int j = 0; j < 4; ++j) {
                int kk = 4 * kc + j;
                float4 z0 = *(const float4*)&zT[kk * ZTS + 8 * half];      // broadcast
                float4 z1 = *(const float4*)&zT[kk * ZTS + 8 * half + 4];  // broadcast
                float w = ww[j];
                a_[0] += z0.x * w; a_[1] += z0.y * w; a_[2] += z0.z * w; a_[3] += z0.w * w;
                a_[4] += z1.x * w; a_[5] += z1.y * w; a_[6] += z1.z * w; a_[7] += z1.w * w;
            }
        }
        float h_[8];
        #pragma unroll
        for (int i = 0; i < 8; ++i) h_[i] = tanh_fast(a_[i]);
        #pragma unroll
        for (int i = 0; i < 8; ++i)
            hRT[(8 * half + i) * HSR + cP1] = h_[i];        // conflict-free b32
        {
            float sc = sL[cP1];
            #pragma unroll
            for (int i = 0; i < 8; ++i) {
                float t = sc * (1.f - h_[i] * h_[i]);
                size_t rho = (size_t)(b0 + 8 * half + i) * Hh + k;
                tg[rho * HID + cP1] = (ushort_t)f2bf_u(t);  // 128 B contiguous / wave
            }
        }

        float unext = 0.f;
        if (tid < 256 && k < Hh - 1) {
            if (fast) {
                #pragma unroll
                for (int it = 0; it < 9; ++it) unext += v9[it];
            } else {
                for (int it = 0; it < nit - 1; ++it) unext += noise[(long)it * NS + nbase];
            }
            unext *= 0.001f;
        }

        __syncthreads();

        // ---- P2: x_next[r][d] = x[r][d] + 0.1 * sum_kk h[r][kk]*W2[kk][d] ----
        float acc0 = 0.f, acc1 = 0.f;
        const int r0 = 2 * rp, r1 = 2 * rp + 1;
        #pragma unroll 4
        for (int j8 = 0; j8 < 32; ++j8) {
            uint4 wv = *(const uint4*)&W2Tu[dP2 * (W2S / 2) + 4 * j8];  // per-lane
            float wf[8];
            unpack8(wv, wf);
            float4 h0a = *(const float4*)&hRT[r0 * HSR + 8 * j8];       // broadcast
            float4 h0b = *(const float4*)&hRT[r0 * HSR + 8 * j8 + 4];
            float4 h1a = *(const float4*)&hRT[r1 * HSR + 8 * j8];
            float4 h1b = *(const float4*)&hRT[r1 * HSR + 8 * j8 + 4];
            float hf0[8] = {h0a.x, h0a.y, h0a.z, h0a.w, h0b.x, h0b.y, h0b.z, h0b.w};
            float hf1[8] = {h1a.x, h1a.y, h1a.z, h1a.w, h1b.x, h1b.y, h1b.z, h1b.w};
            #pragma unroll
            for (int jj = 0; jj < 8; ++jj) {   // kk-sequential, order preserved
                acc0 += hf0[jj] * wf[jj];
                acc1 += hf1[jj] * wf[jj];
            }
        }
        {
            const int bb0 = b0 + r0, bb1 = b0 + r1;
            float xn0 = zT[dP2 * ZTS + r0] + 0.1f * acc0;
            float xn1 = zT[dP2 * ZTS + r1] + 0.1f * acc1;
            out[O1 + bb0 * XT_PITCH + (k + 1) * NX + dP2] = xn0;
            out[O2 + bb0 * PR_PITCH + k * NX + dP2] = xn0;
            out[O1 + bb1 * XT_PITCH + (k + 1) * NX + dP2] = xn1;
            out[O2 + bb1 * PR_PITCH + k * NX + dP2] = xn1;
            zT[dP2 * ZTS + r0] = xn0;
            zT[dP2 * ZTS + r1] = xn1;
            if (tid < 256 && k < Hh - 1) zT[(NX + q16n) * ZTS + r16n] = unext;
        }
    }
}

// =====================================================================
// K2: G[204800 x 80] = T[204800 x 256] @ W1^T, bf16 MFMA 16x16x32.
// A-fragments straight from global; only W1-bf16 in LDS. (unchanged)
// =====================================================================
__global__ __launch_bounds__(256) void ker_lin2(const float* __restrict__ W1,
                                                const ushort_t* __restrict__ Tg,
                                                float* __restrict__ out) {
    __shared__ __align__(16) ushort_t W1b[NXU * TLS];   // 42,240 B (only LDS)

    const int tid = threadIdx.x;
    const int r0 = blockIdx.x * 128;

    {
        const float4* W1f4 = (const float4*)W1;
        for (int i = tid; i < (NXU * HID) / 4; i += 256) {
            float4 w = W1f4[i];
            int p = i >> 6, c4 = i & 63;
            uint2 pk = make_uint2(f2bf_u(w.x) | (f2bf_u(w.y) << 16),
                                  f2bf_u(w.z) | (f2bf_u(w.w) << 16));
            *(uint2*)&W1b[p * TLS + 4 * c4] = pk;
        }
    }
    __syncthreads();

    const int wv = tid >> 6, lane = tid & 63;
    const int m = lane & 15, quad = lane >> 4;

    f32x4_t acc[2][5];
    #pragma unroll
    for (int i = 0; i < 2; ++i)
        #pragma unroll
        for (int j = 0; j < 5; ++j) acc[i][j] = (f32x4_t){0.f, 0.f, 0.f, 0.f};

    const ushort_t* Ta = Tg + (size_t)(r0 + wv * 32 + m) * HID;
    const ushort_t* Tb = Ta + (size_t)16 * HID;

    #pragma unroll
    for (int kc = 0; kc < 8; ++kc) {
        const int koff = kc * 32 + quad * 8;
        bf16x8_t a0 = *(const bf16x8_t*)&Ta[koff];
        bf16x8_t a1 = *(const bf16x8_t*)&Tb[koff];
        #pragma unroll
        for (int nt = 0; nt < 5; ++nt) {
            bf16x8_t bfr = *(const bf16x8_t*)&W1b[(nt * 16 + m) * TLS + koff];
            acc[0][nt] = __builtin_amdgcn_mfma_f32_16x16x32_bf16(a0, bfr, acc[0][nt], 0, 0, 0);
            acc[1][nt] = __builtin_amdgcn_mfma_f32_16x16x32_bf16(a1, bfr, acc[1][nt], 0, 0, 0);
        }
    }

    #pragma unroll
    for (int mt = 0; mt < 2; ++mt) {
        int rbase = r0 + wv * 32 + mt * 16 + quad * 4;
        #pragma unroll
        for (int r = 0; r < 4; ++r) {
            int rho = rbase + r;
            int b = (int)(((unsigned long long)rho * 1374389535ULL) >> 36);  // rho/50
            int kk = rho - b * 50;
            float* gxp = out + O3 + (size_t)b * PR_PITCH + kk * NX + m;
            #pragma unroll
            for (int nt = 0; nt < 4; ++nt)
                gxp[nt * 16] = 1.0f + acc[mt][nt][r];
            out[O4 + (size_t)b * U_PITCH + kk * NU + m] = acc[mt][4][r];
        }
    }
}

// =====================================================================
// Fallback: R2's proven fused kernel (used only if ws_size is too small)
// =====================================================================
__global__ __launch_bounds__(256) void ker_fused(const float* __restrict__ x0,
                                                 const float* __restrict__ W1,
                                                 const float* __restrict__ b1,
                                                 const float* __restrict__ W2,
                                                 const float* __restrict__ noise,
                                                 const int* __restrict__ nit_p,
                                                 float* __restrict__ out) {
    __shared__ __align__(16) float    W1L[NXU * W1S];
    __shared__ __align__(16) ushort_t W2T[NX * W2S];
    __shared__ __align__(16) float    hRT[16 * HS];
    __shared__ __align__(16) ushort_t tT[16 * TS];
    __shared__ __align__(16) float    zT[NXU * 16];
    __shared__ float b1L[HID];
    __shared__ float sL[HID];

    const int tid = threadIdx.x;
    const int b0 = blockIdx.x * 16;
    const int nit = nit_p[0];

    for (int i = tid; i < NXU * HID; i += 256)
        W1L[(i >> 8) * W1S + (i & 255)] = W1[i];
    for (int i = tid; i < HID * NX; i += 256) {
        int c = i >> 6, d = i & 63;
        W2T[d * W2S + c] = (ushort_t)f2bf_u(W2[i]);
    }
    b1L[tid] = b1[tid];
    for (int i = tid; i < 16 * NX; i += 256) {
        int r = i >> 6, d = i & 63;
        float v = x0[(b0 + r) * NX + d];
        zT[d * 16 + r] = v;
        out[O1 + (b0 + r) * XT_PITCH + d] = v;
    }
    const int r16 = tid >> 4, q16 = tid & 15;
    {
        long base = (long)(b0 + r16) * U_PITCH + q16;
        float s = 0.f;
        for (int it = 0; it < nit - 1; ++it) s += noise[(long)it * NS + base];
        zT[(NX + q16) * 16 + r16] = 0.001f * s;
        out[(b0 + r16) * NU + q16] = 0.001f * (s + noise[(long)(nit - 1) * NS + base]);
    }
    __syncthreads();
    {
        float s = 0.f;
        for (int d = 0; d < NX; ++d) s += bf2f(W2T[d * W2S + tid]);
        sL[tid] = 0.1f * s;
    }

    const int ct = tid & 63, rt = tid >> 6;
    uint* tTu = (uint*)tT;
    const uint* W2Tu = (const uint*)W2T;

    for (int k = 0; k < Hh; ++k) {
        __syncthreads();
        float v9[9];
        const bool fast = (k < Hh - 1) && (nit == 10);
        long nbase = (long)(b0 + r16) * U_PITCH + (k + 1) * NU + q16;
        if (fast) {
            #pragma unroll
            for (int it = 0; it < 9; ++it) v9[it] = noise[(long)it * NS + nbase];
        }
        float a_[4][4];
        {
            float bj[4];
            #pragma unroll
            for (int j = 0; j < 4; ++j) bj[j] = b1L[4 * ct + j];
            #pragma unroll
            for (int i = 0; i < 4; ++i)
                #pragma unroll
                for (int j = 0; j < 4; ++j) a_[i][j] = bj[j];
        }
        #pragma unroll 8
        for (int kk = 0; kk < NXU; ++kk) {
            float4 zv = *(const float4*)&zT[kk * 16 + 4 * rt];
            float4 wv = *(const float4*)&W1L[kk * W1S + 4 * ct];
            float zz[4] = {zv.x, zv.y, zv.z, zv.w};
            float ww[4] = {wv.x, wv.y, wv.z, wv.w};
            #pragma unroll
            for (int i = 0; i < 4; ++i)
                #pragma unroll
                for (int j = 0; j < 4; ++j) a_[i][j] += zz[i] * ww[j];
        }
        float h_[4][4];
        #pragma unroll
        for (int i = 0; i < 4; ++i)
            #pragma unroll
            for (int j = 0; j < 4; ++j) h_[i][j] = tanh_fast(a_[i][j]);
        #pragma unroll
        for (int i = 0; i < 4; ++i)
            *(float4*)&hRT[(4 * rt + i) * HS + 4 * ct] =
                make_float4(h_[i][0], h_[i][1], h_[i][2], h_[i][3]);
        {
            float s0 = sL[4 * ct], s1 = sL[4 * ct + 1], s2 = sL[4 * ct + 2], s3 = sL[4 * ct + 3];
            #pragma unroll
            for (int i = 0; i < 4; ++i) {
                float t0 = s0 * (1.f - h_[i][0] * h_[i][0]);
                float t1 = s1 * (1.f - h_[i][1] * h_[i][1]);
                float t2 = s2 * (1.f - h_[i][2] * h_[i][2]);
                float t3 = s3 * (1.f - h_[i][3] * h_[i][3]);
                tTu[(4 * rt + i) * (TS / 2) + 2 * ct]     = f2bf_u(t0) | (f2bf_u(t1) << 16);
                tTu[(4 * rt + i) * (TS / 2) + 2 * ct + 1] = f2bf_u(t2) | (f2bf_u(t3) << 16);
            }
        }
        float unext = 0.f;
        if (k < Hh - 1) {
            if (fast) {
                #pragma unroll
                for (int it = 0; it < 9; ++it) unext += v9[it];
            } else {
                for (int it = 0; it < nit - 1; ++it) unext += noise[(long)it * NS + nbase];
            }
            unext *= 0.001f;
        }
        __syncthreads();
        float xacc[4] = {0.f, 0.f, 0.f, 0.f};
        #pragma unroll 4
        for (int c8 = 0; c8 < HID / 8; ++c8) {
            float4 h0 = *(const float4*)&hRT[r16 * HS + 8 * c8];
            float4 h1 = *(const float4*)&hRT[r16 * HS + 8 * c8 + 4];
            float hf[8] = {h0.x, h0.y, h0.z, h0.w, h1.x, h1.y, h1.z, h1.w};
            #pragma unroll
            for (int i = 0; i < 4; ++i) {
                int d = q16 + 16 * i;
                uint4 wv = *(const uint4*)&W2Tu[d * (W2S / 2) + 4 * c8];
                float wf[8];
                unpack8(wv, wf);
                #pragma unroll
                for (int jj = 0; jj < 8; ++jj) xacc[i] += hf[jj] * wf[jj];
            }
        }
        {
            const int bb = b0 + r16;
            #pragma unroll
            for (int i = 0; i < 4; ++i) {
                int d = q16 + 16 * i;
                float xn = zT[d * 16 + r16] + 0.1f * xacc[i];
                out[O1 + bb * XT_PITCH + (k + 1) * NX + d] = xn;
                out[O2 + bb * PR_PITCH + k * NX + d] = xn;
                zT[d * 16 + r16] = xn;
            }
            if (k < Hh - 1) zT[(NX + q16) * 16 + r16] = unext;
        }
        {
            const uint* tTr = (const uint*)tT + r16 * (TS / 2);
            float g_[5] = {0.f, 0.f, 0.f, 0.f, 0.f};
            #pragma unroll 4
            for (int jc = 0; jc < HID / 8; ++jc) {
                uint4 tv = *(const uint4*)&tTr[4 * jc];
                float tf[8];
                unpack8(tv, tf);
                #pragma unroll
                for (int i = 0; i < 5; ++i) {
                    int p = q16 + 16 * i;
                    float4 w0 = *(const float4*)&W1L[p * W1S + 8 * jc];
                    float4 w1 = *(const float4*)&W1L[p * W1S + 8 * jc + 4];
                    g_[i] += tf[0] * w0.x + tf[1] * w0.y + tf[2] * w0.z + tf[3] * w0.w
                           + tf[4] * w1.x + tf[5] * w1.y + tf[6] * w1.z + tf[7] * w1.w;
                }
            }
            const int bb = b0 + r16;
            #pragma unroll
            for (int i = 0; i < 4; ++i)
                out[O3 + bb * PR_PITCH + k * NX + (q16 + 16 * i)] = 1.0f + g_[i];
            out[O4 + bb * U_PITCH + k * NU + q16] = g_[4];
        }
    }
}

extern "C" void kernel_launch(void* const* d_in, const int* in_sizes, int n_in,
                              void* d_out, int out_size, void* d_ws, size_t ws_size,
                              hipStream_t stream) {
    const float* x0    = (const float*)d_in[0];
    // d_in[1] = xref (unused)
    const float* W1    = (const float*)d_in[2];
    const float* b1    = (const float*)d_in[3];
    const float* W2    = (const float*)d_in[4];
    const float* noise = (const float*)d_in[5];
    const int*   nit   = (const int*)d_in[6];
    float* out = (float*)d_out;

    if (ws_size >= (size_t)T_BYTES) {
        ushort_t* tg = (ushort_t*)d_ws;
        ker_roll<<<Bsz / 16, 512, 0, stream>>>(x0, W1, b1, W2, noise, nit, out, tg);
        ker_lin2<<<(Bsz * Hh) / 128, 256, 0, stream>>>(W1, tg, out);
    } else {
        ker_fused<<<Bsz / 16, 256, 0, stream>>>(x0, W1, b1, W2, noise, nit, out);
    }
}

// Round 5
// 673.863 us; speedup vs baseline: 1.1198x; 1.1198x over previous
//
#include <hip/hip_runtime.h>

typedef unsigned int uint;
typedef unsigned short ushort_t;
typedef __attribute__((ext_vector_type(8))) short bf16x8_t;   // 8 bf16 (4 VGPRs)
typedef __attribute__((ext_vector_type(4))) float f32x4_t;    // MFMA acc

// Problem constants
constexpr int Bsz = 4096, NX = 64, NU = 16, NXU = 80, HID = 256, Hh = 50;
constexpr long NS = (long)Bsz * Hh * NU;   // noise per-iteration stride: 3,276,800
// Output offsets (floats), concatenated in return order
constexpr int O1 = 65536;                  // x_traj  (B,51,64)
constexpr int O2 = 13434880;               // pred    (B,50,64)
constexpr int O3 = 26542080;               // gx      (B,50,64)
constexpr int O4 = 39649280;               // gu      (B,50,16)
constexpr int XT_PITCH = (Hh + 1) * NX;    // 3264
constexpr int PR_PITCH = Hh * NX;          // 3200
constexpr int U_PITCH = Hh * NU;           // 800

// ker_roll geometry
constexpr int RB = 8;      // batch rows per block -> 512 blocks, 2 blocks/CU

// LDS strides (padded)
constexpr int W1S  = 260;  // fallback: W1L row stride (floats)
constexpr int HS   = 264;  // fallback hRT stride
constexpr int HSR  = 260;  // ker_roll hRT [r][kk] stride (floats)
constexpr int ZT8  = 12;   // ker_roll zT [kk][8] stride (floats); 48 B, float4-aligned
constexpr int TS   = 264;  // tT row stride (shorts)   (fallback kernel only)
constexpr int W2S  = 264;  // W2T row stride (shorts)
constexpr int TLS  = 264;  // K2 LDS row stride (shorts); 264*2=528 B, 16B-aligned

constexpr long T_BYTES = (long)Bsz * Hh * HID * 2;   // 104,857,600 B in d_ws

__device__ __forceinline__ float tanh_fast(float x) {
    float e = __expf(2.0f * x);
    return 1.0f - 2.0f / (e + 1.0f);   // safe at +/-inf
}
__device__ __forceinline__ uint f2bf_u(float x) {
    uint b = __float_as_uint(x);
    return (b + 0x7FFFu + ((b >> 16) & 1u)) >> 16;   // RNE, low 16 bits valid
}
__device__ __forceinline__ float bf2f(ushort_t u) {
    return __uint_as_float(((uint)u) << 16);
}
__device__ __forceinline__ void unpack8(uint4 v, float* f) {
    f[0] = __uint_as_float(v.x << 16); f[1] = __uint_as_float(v.x & 0xFFFF0000u);
    f[2] = __uint_as_float(v.y << 16); f[3] = __uint_as_float(v.y & 0xFFFF0000u);
    f[4] = __uint_as_float(v.z << 16); f[5] = __uint_as_float(v.z & 0xFFFF0000u);
    f[6] = __uint_as_float(v.w << 16); f[7] = __uint_as_float(v.w & 0xFFFF0000u);
}

// =====================================================================
// K1: sequential rollout, 8 batch rows/block, 512 blocks, 256 threads.
// KEY CHANGE (R4 post-mortem): the kernel is latency/barrier-bound with
// 1 block/CU (dur invariant across VALU/LDS restructurings). W1 moves
// from LDS into per-thread registers (each P1 thread uses exactly one
// 80-float column), shrinking LDS to ~48 KB -> 2 blocks/CU. Two
// independent barrier groups per CU overlap each other's barrier/store
// drains. Per-output kk order unchanged -> bitwise-identical outputs.
//   P1: thread c=tid owns a[0..7][c]; z broadcast from LDS, W1 in regs.
//   P2: thread (rp=tid>>6, d=tid&63) owns x[2 rows][col d]; bf16 W2 LDS.
// =====================================================================
__global__ __launch_bounds__(256, 2) void ker_roll(const float* __restrict__ x0,
                                                   const float* __restrict__ W1,
                                                   const float* __restrict__ b1,
                                                   const float* __restrict__ W2,
                                                   const float* __restrict__ noise,
                                                   const int* __restrict__ nit_p,
                                                   float* __restrict__ out,
                                                   ushort_t* __restrict__ tg) {
    __shared__ __align__(16) ushort_t W2T[NX * W2S];    // 33,792 B  [d][c]
    __shared__ __align__(16) float    hRT[RB * HSR];    //  8,320 B  [r][kk]
    __shared__ __align__(16) float    zT[NXU * ZT8];    //  3,840 B  [kk][8]
    __shared__ float b1L[HID];                          //  1,024 B
    __shared__ float sL[HID];                           //  1,024 B
    // total 48,000 B -> 2 blocks (8 waves) / CU

    const int tid = threadIdx.x;
    const int b0 = blockIdx.x * RB;
    const int nit = nit_p[0];

    // W1 column c=tid into registers (80 VGPRs), coalesced per kk
    float w1r[NXU];
    #pragma unroll
    for (int kk = 0; kk < NXU; ++kk) w1r[kk] = W1[kk * HID + tid];

    for (int i = tid; i < HID * NX; i += 256) {
        int c = i >> 6, d = i & 63;
        W2T[d * W2S + c] = (ushort_t)f2bf_u(W2[i]);
    }
    b1L[tid] = b1[tid];
    for (int i = tid; i < RB * NX; i += 256) {
        int r = i >> 6, d = i & 63;
        float v = x0[(b0 + r) * NX + d];
        zT[d * ZT8 + r] = v;
        out[O1 + (b0 + r) * XT_PITCH + d] = v;
    }
    const int r16n = tid >> 4, q16n = tid & 15;   // control tile: tid<128 -> r16n 0..7
    if (tid < 16 * RB) {
        long base = (long)(b0 + r16n) * U_PITCH + q16n;
        float s = 0.f;
        for (int it = 0; it < nit - 1; ++it) s += noise[(long)it * NS + base];
        zT[(NX + q16n) * ZT8 + r16n] = 0.001f * s;
        out[(b0 + r16n) * NU + q16n] = 0.001f * (s + noise[(long)(nit - 1) * NS + base]);
    }
    __syncthreads();
    {
        float s = 0.f;
        for (int d = 0; d < NX; ++d) s += bf2f(W2T[d * W2S + tid]);
        sL[tid] = 0.1f * s;   // consumed after loop-top barrier
    }

    const int c = tid;                          // P1: col c, rows 0..7
    const int dP2 = tid & 63, rp = tid >> 6;    // P2: rows {2rp,2rp+1}, col dP2
    const uint* W2Tu = (const uint*)W2T;

    for (int k = 0; k < Hh; ++k) {
        __syncthreads();

        // prefetch next-step controls (tid<128 handles the 8x16 control tile)
        float v9[9];
        const bool fast = (k < Hh - 1) && (nit == 10);
        long nbase = (long)(b0 + r16n) * U_PITCH + (k + 1) * NU + q16n;
        if (fast && tid < 16 * RB) {
            #pragma unroll
            for (int it = 0; it < 9; ++it) v9[it] = noise[(long)it * NS + nbase];
        }

        // ---- P1: a[r][c] = b1[c] + sum_kk z[r][kk]*W1[kk][c]  (W1 in regs) ----
        float a_[RB];
        {
            float bj = b1L[c];
            #pragma unroll
            for (int i = 0; i < RB; ++i) a_[i] = bj;
        }
        #pragma unroll
        for (int kk = 0; kk < NXU; ++kk) {
            float4 z0 = *(const float4*)&zT[kk * ZT8];       // broadcast (rows 0-3)
            float4 z1 = *(const float4*)&zT[kk * ZT8 + 4];   // broadcast (rows 4-7)
            float w = w1r[kk];
            a_[0] += z0.x * w; a_[1] += z0.y * w; a_[2] += z0.z * w; a_[3] += z0.w * w;
            a_[4] += z1.x * w; a_[5] += z1.y * w; a_[6] += z1.z * w; a_[7] += z1.w * w;
        }
        float h_[RB];
        #pragma unroll
        for (int i = 0; i < RB; ++i) h_[i] = tanh_fast(a_[i]);
        #pragma unroll
        for (int i = 0; i < RB; ++i)
            hRT[i * HSR + c] = h_[i];           // lanes contiguous in c: conflict-free
        {
            float sc = sL[c];
            #pragma unroll
            for (int i = 0; i < RB; ++i) {
                float t = sc * (1.f - h_[i] * h_[i]);
                size_t rho = (size_t)(b0 + i) * Hh + k;
                tg[rho * HID + c] = (ushort_t)f2bf_u(t);   // 512 B contiguous / row
            }
        }

        float unext = 0.f;
        if (tid < 16 * RB && k < Hh - 1) {
            if (fast) {
                #pragma unroll
                for (int it = 0; it < 9; ++it) unext += v9[it];
            } else {
                for (int it = 0; it < nit - 1; ++it) unext += noise[(long)it * NS + nbase];
            }
            unext *= 0.001f;
        }

        __syncthreads();

        // ---- P2: x_next[r][d] = x[r][d] + 0.1 * sum_kk h[r][kk]*W2[kk][d] ----
        float acc0 = 0.f, acc1 = 0.f;
        const int r0 = 2 * rp, r1 = 2 * rp + 1;
        #pragma unroll 4
        for (int j8 = 0; j8 < 32; ++j8) {
            uint4 wv = *(const uint4*)&W2Tu[dP2 * (W2S / 2) + 4 * j8];  // per-lane
            float wf[8];
            unpack8(wv, wf);
            float4 h0a = *(const float4*)&hRT[r0 * HSR + 8 * j8];       // broadcast x16
            float4 h0b = *(const float4*)&hRT[r0 * HSR + 8 * j8 + 4];
            float4 h1a = *(const float4*)&hRT[r1 * HSR + 8 * j8];
            float4 h1b = *(const float4*)&hRT[r1 * HSR + 8 * j8 + 4];
            float hf0[8] = {h0a.x, h0a.y, h0a.z, h0a.w, h0b.x, h0b.y, h0b.z, h0b.w};
            float hf1[8] = {h1a.x, h1a.y, h1a.z, h1a.w, h1b.x, h1b.y, h1b.z, h1b.w};
            #pragma unroll
            for (int jj = 0; jj < 8; ++jj) {   // kk-sequential, order preserved
                acc0 += hf0[jj] * wf[jj];
                acc1 += hf1[jj] * wf[jj];
            }
        }
        {
            const int bb0 = b0 + r0, bb1 = b0 + r1;
            float xn0 = zT[dP2 * ZT8 + r0] + 0.1f * acc0;
            float xn1 = zT[dP2 * ZT8 + r1] + 0.1f * acc1;
            out[O1 + bb0 * XT_PITCH + (k + 1) * NX + dP2] = xn0;
            out[O2 + bb0 * PR_PITCH + k * NX + dP2] = xn0;
            out[O1 + bb1 * XT_PITCH + (k + 1) * NX + dP2] = xn1;
            out[O2 + bb1 * PR_PITCH + k * NX + dP2] = xn1;
            zT[dP2 * ZT8 + r0] = xn0;
            zT[dP2 * ZT8 + r1] = xn1;
            if (tid < 16 * RB && k < Hh - 1) zT[(NX + q16n) * ZT8 + r16n] = unext;
        }
    }
}

// =====================================================================
// K2: G[204800 x 80] = T[204800 x 256] @ W1^T, bf16 MFMA 16x16x32.
// A-fragments straight from global; only W1-bf16 in LDS. (unchanged)
// =====================================================================
__global__ __launch_bounds__(256) void ker_lin2(const float* __restrict__ W1,
                                                const ushort_t* __restrict__ Tg,
                                                float* __restrict__ out) {
    __shared__ __align__(16) ushort_t W1b[NXU * TLS];   // 42,240 B (only LDS)

    const int tid = threadIdx.x;
    const int r0 = blockIdx.x * 128;

    {
        const float4* W1f4 = (const float4*)W1;
        for (int i = tid; i < (NXU * HID) / 4; i += 256) {
            float4 w = W1f4[i];
            int p = i >> 6, c4 = i & 63;
            uint2 pk = make_uint2(f2bf_u(w.x) | (f2bf_u(w.y) << 16),
                                  f2bf_u(w.z) | (f2bf_u(w.w) << 16));
            *(uint2*)&W1b[p * TLS + 4 * c4] = pk;
        }
    }
    __syncthreads();

    const int wv = tid >> 6, lane = tid & 63;
    const int m = lane & 15, quad = lane >> 4;

    f32x4_t acc[2][5];
    #pragma unroll
    for (int i = 0; i < 2; ++i)
        #pragma unroll
        for (int j = 0; j < 5; ++j) acc[i][j] = (f32x4_t){0.f, 0.f, 0.f, 0.f};

    const ushort_t* Ta = Tg + (size_t)(r0 + wv * 32 + m) * HID;
    const ushort_t* Tb = Ta + (size_t)16 * HID;

    #pragma unroll
    for (int kc = 0; kc < 8; ++kc) {
        const int koff = kc * 32 + quad * 8;
        bf16x8_t a0 = *(const bf16x8_t*)&Ta[koff];
        bf16x8_t a1 = *(const bf16x8_t*)&Tb[koff];
        #pragma unroll
        for (int nt = 0; nt < 5; ++nt) {
            bf16x8_t bfr = *(const bf16x8_t*)&W1b[(nt * 16 + m) * TLS + koff];
            acc[0][nt] = __builtin_amdgcn_mfma_f32_16x16x32_bf16(a0, bfr, acc[0][nt], 0, 0, 0);
            acc[1][nt] = __builtin_amdgcn_mfma_f32_16x16x32_bf16(a1, bfr, acc[1][nt], 0, 0, 0);
        }
    }

    #pragma unroll
    for (int mt = 0; mt < 2; ++mt) {
        int rbase = r0 + wv * 32 + mt * 16 + quad * 4;
        #pragma unroll
        for (int r = 0; r < 4; ++r) {
            int rho = rbase + r;
            int b = (int)(((unsigned long long)rho * 1374389535ULL) >> 36);  // rho/50
            int kk = rho - b * 50;
            float* gxp = out + O3 + (size_t)b * PR_PITCH + kk * NX + m;
            #pragma unroll
            for (int nt = 0; nt < 4; ++nt)
                gxp[nt * 16] = 1.0f + acc[mt][nt][r];
            out[O4 + (size_t)b * U_PITCH + kk * NU + m] = acc[mt][4][r];
        }
    }
}

// =====================================================================
// Fallback: R2's proven fused kernel (used only if ws_size is too small)
// =====================================================================
__global__ __launch_bounds__(256) void ker_fused(const float* __restrict__ x0,
                                                 const float* __restrict__ W1,
                                                 const float* __restrict__ b1,
                                                 const float* __restrict__ W2,
                                                 const float* __restrict__ noise,
                                                 const int* __restrict__ nit_p,
                                                 float* __restrict__ out) {
    __shared__ __align__(16) float    W1L[NXU * W1S];
    __shared__ __align__(16) ushort_t W2T[NX * W2S];
    __shared__ __align__(16) float    hRT[16 * HS];
    __shared__ __align__(16) ushort_t tT[16 * TS];
    __shared__ __align__(16) float    zT[NXU * 16];
    __shared__ float b1L[HID];
    __shared__ float sL[HID];

    const int tid = threadIdx.x;
    const int b0 = blockIdx.x * 16;
    const int nit = nit_p[0];

    for (int i = tid; i < NXU * HID; i += 256)
        W1L[(i >> 8) * W1S + (i & 255)] = W1[i];
    for (int i = tid; i < HID * NX; i += 256) {
        int c = i >> 6, d = i & 63;
        W2T[d * W2S + c] = (ushort_t)f2bf_u(W2[i]);
    }
    b1L[tid] = b1[tid];
    for (int i = tid; i < 16 * NX; i += 256) {
        int r = i >> 6, d = i & 63;
        float v = x0[(b0 + r) * NX + d];
        zT[d * 16 + r] = v;
        out[O1 + (b0 + r) * XT_PITCH + d] = v;
    }
    const int r16 = tid >> 4, q16 = tid & 15;
    {
        long base = (long)(b0 + r16) * U_PITCH + q16;
        float s = 0.f;
        for (int it = 0; it < nit - 1; ++it) s += noise[(long)it * NS + base];
        zT[(NX + q16) * 16 + r16] = 0.001f * s;
        out[(b0 + r16) * NU + q16] = 0.001f * (s + noise[(long)(nit - 1) * NS + base]);
    }
    __syncthreads();
    {
        float s = 0.f;
        for (int d = 0; d < NX; ++d) s += bf2f(W2T[d * W2S + tid]);
        sL[tid] = 0.1f * s;
    }

    const int ct = tid & 63, rt = tid >> 6;
    uint* tTu = (uint*)tT;
    const uint* W2Tu = (const uint*)W2T;

    for (int k = 0; k < Hh; ++k) {
        __syncthreads();
        float v9[9];
        const bool fast = (k < Hh - 1) && (nit == 10);
        long nbase = (long)(b0 + r16) * U_PITCH + (k + 1) * NU + q16;
        if (fast) {
            #pragma unroll
            for (int it = 0; it < 9; ++it) v9[it] = noise[(long)it * NS + nbase];
        }
        float a_[4][4];
        {
            float bj[4];
            #pragma unroll
            for (int j = 0; j < 4; ++j) bj[j] = b1L[4 * ct + j];
            #pragma unroll
            for (int i = 0; i < 4; ++i)
                #pragma unroll
                for (int j = 0; j < 4; ++j) a_[i][j] = bj[j];
        }
        #pragma unroll 8
        for (int kk = 0; kk < NXU; ++kk) {
            float4 zv = *(const float4*)&zT[kk * 16 + 4 * rt];
            float4 wv = *(const float4*)&W1L[kk * W1S + 4 * ct];
            float zz[4] = {zv.x, zv.y, zv.z, zv.w};
            float ww[4] = {wv.x, wv.y, wv.z, wv.w};
            #pragma unroll
            for (int i = 0; i < 4; ++i)
                #pragma unroll
                for (int j = 0; j < 4; ++j) a_[i][j] += zz[i] * ww[j];
        }
        float h_[4][4];
        #pragma unroll
        for (int i = 0; i < 4; ++i)
            #pragma unroll
            for (int j = 0; j < 4; ++j) h_[i][j] = tanh_fast(a_[i][j]);
        #pragma unroll
        for (int i = 0; i < 4; ++i)
            *(float4*)&hRT[(4 * rt + i) * HS + 4 * ct] =
                make_float4(h_[i][0], h_[i][1], h_[i][2], h_[i][3]);
        {
            float s0 = sL[4 * ct], s1 = sL[4 * ct + 1], s2 = sL[4 * ct + 2], s3 = sL[4 * ct + 3];
            #pragma unroll
            for (int i = 0; i < 4; ++i) {
                float t0 = s0 * (1.f - h_[i][0] * h_[i][0]);
                float t1 = s1 * (1.f - h_[i][1] * h_[i][1]);
                float t2 = s2 * (1.f - h_[i][2] * h_[i][2]);
                float t3 = s3 * (1.f - h_[i][3] * h_[i][3]);
                tTu[(4 * rt + i) * (TS / 2) + 2 * ct]     = f2bf_u(t0) | (f2bf_u(t1) << 16);
                tTu[(4 * rt + i) * (TS / 2) + 2 * ct + 1] = f2bf_u(t2) | (f2bf_u(t3) << 16);
            }
        }
        float unext = 0.f;
        if (k < Hh - 1) {
            if (fast) {
                #pragma unroll
                for (int it = 0; it < 9; ++it) unext += v9[it];
            } else {
                for (int it = 0; it < nit - 1; ++it) unext += noise[(long)it * NS + nbase];
            }
            unext *= 0.001f;
        }
        __syncthreads();
        float xacc[4] = {0.f, 0.f, 0.f, 0.f};
        #pragma unroll 4
        for (int c8 = 0; c8 < HID / 8; ++c8) {
            float4 h0 = *(const float4*)&hRT[r16 * HS + 8 * c8];
            float4 h1 = *(const float4*)&hRT[r16 * HS + 8 * c8 + 4];
            float hf[8] = {h0.x, h0.y, h0.z, h0.w, h1.x, h1.y, h1.z, h1.w};
            #pragma unroll
            for (int i = 0; i < 4; ++i) {
                int d = q16 + 16 * i;
                uint4 wv = *(const uint4*)&W2Tu[d * (W2S / 2) + 4 * c8];
                float wf[8];
                unpack8(wv, wf);
                #pragma unroll
                for (int jj = 0; jj < 8; ++jj) xacc[i] += hf[jj] * wf[jj];
            }
        }
        {
            const int bb = b0 + r16;
            #pragma unroll
            for (int i = 0; i < 4; ++i) {
                int d = q16 + 16 * i;
                float xn = zT[d * 16 + r16] + 0.1f * xacc[i];
                out[O1 + bb * XT_PITCH + (k + 1) * NX + d] = xn;
                out[O2 + bb * PR_PITCH + k * NX + d] = xn;
                zT[d * 16 + r16] = xn;
            }
            if (k < Hh - 1) zT[(NX + q16) * 16 + r16] = unext;
        }
        {
            const uint* tTr = (const uint*)tT + r16 * (TS / 2);
            float g_[5] = {0.f, 0.f, 0.f, 0.f, 0.f};
            #pragma unroll 4
            for (int jc = 0; jc < HID / 8; ++jc) {
                uint4 tv = *(const uint4*)&tTr[4 * jc];
                float tf[8];
                unpack8(tv, tf);
                #pragma unroll
                for (int i = 0; i < 5; ++i) {
                    int p = q16 + 16 * i;
                    float4 w0 = *(const float4*)&W1L[p * W1S + 8 * jc];
                    float4 w1 = *(const float4*)&W1L[p * W1S + 8 * jc + 4];
                    g_[i] += tf[0] * w0.x + tf[1] * w0.y + tf[2] * w0.z + tf[3] * w0.w
                           + tf[4] * w1.x + tf[5] * w1.y + tf[6] * w1.z + tf[7] * w1.w;
                }
            }
            const int bb = b0 + r16;
            #pragma unroll
            for (int i = 0; i < 4; ++i)
                out[O3 + bb * PR_PITCH + k * NX + (q16 + 16 * i)] = 1.0f + g_[i];
            out[O4 + bb * U_PITCH + k * NU + q16] = g_[4];
        }
    }
}

extern "C" void kernel_launch(void* const* d_in, const int* in_sizes, int n_in,
                              void* d_out, int out_size, void* d_ws, size_t ws_size,
                              hipStream_t stream) {
    const float* x0    = (const float*)d_in[0];
    // d_in[1] = xref (unused)
    const float* W1    = (const float*)d_in[2];
    const float* b1    = (const float*)d_in[3];
    const float* W2    = (const float*)d_in[4];
    const float* noise = (const float*)d_in[5];
    const int*   nit   = (const int*)d_in[6];
    float* out = (float*)d_out;

    if (ws_size >= (size_t)T_BYTES) {
        ushort_t* tg = (ushort_t*)d_ws;
        ker_roll<<<Bsz / RB, 256, 0, stream>>>(x0, W1, b1, W2, noise, nit, out, tg);
        ker_lin2<<<(Bsz * Hh) / 128, 256, 0, stream>>>(W1, tg, out);
    } else {
        ker_fused<<<Bsz / 16, 256, 0, stream>>>(x0, W1, b1, W2, noise, nit, out);
    }
}